// Round 17
// baseline (164.440 us; speedup 1.0000x reference)
//
#include <hip/hip_runtime.h>
#include <math.h>

// ---------------- problem constants ----------------
#define NB        512
#define ND        32
#define NCOND     30
#define NS        21                  // NB_STEPS+1 quadrature nodes
#define NBD       (NB*ND)             // 16384
#define BDPB      3                   // bd-groups per block (63 rows + 1 pad)
#define NBLK      ((NBD + BDPB - 1) / BDPB)   // 5462 blocks

// packed-weight element counts (ushort), 32x32x16 fragment layout:
//   p = ((kstep16*8 + ct)*64 + lane)*8 + i
//     holds W[kstep*16 + (lane>>5)*8 + i][ct*32 + (lane&31)]
#define W0P_ELEMS (2*8*64*8)          // 8192  (K=32 -> 2 ksteps, pad 31->32)
#define W1P_ELEMS (16*8*64*8)         // 65536 (K=256 -> 16 ksteps)
#define W3P_ELEMS (16*64*8)           // 8192  (A-frag, 32 neurons, row0 only)
#define WP_TOTAL  (W0P_ELEMS + 2*W1P_ELEMS + W3P_ELEMS)  // 147456

typedef __bf16 bf8 __attribute__((ext_vector_type(8)));
typedef float  fx16 __attribute__((ext_vector_type(16)));
typedef unsigned short us8 __attribute__((ext_vector_type(8)));

__device__ __forceinline__ unsigned short f2bf(float f) {
  unsigned int u = __float_as_uint(f);
  u += 0x7FFFu + ((u >> 16) & 1u);        // round-to-nearest-even
  return (unsigned short)(u >> 16);
}

// ---------------- kernel 1: pack weights + Clenshaw-Curtis weights ----------
__global__ void prep_pack(const float* __restrict__ W0,
                          const float* __restrict__ W1,
                          const float* __restrict__ W2,
                          const float* __restrict__ W3,
                          unsigned short* __restrict__ wp,
                          float* __restrict__ ccwbuf) {
  if (blockIdx.x == 0 && threadIdx.x < NS) {   // cc weights (double prec, once)
    int tid = threadIdx.x;
    double acc = 0.0;
#pragma unroll
    for (int i = 0; i <= 20; i += 2) {
      double wi = (i == 0) ? 1.0 : 2.0 / (1.0 - (double)(i * i));
      acc += cos((double)(i * tid) * 3.141592653589793 / 20.0) * wi;
    }
    double edge = (tid == 0 || tid == 20) ? 0.5 : 1.0;
    ccwbuf[tid] = (float)(acc * 0.1 * edge);
  }
  int t = blockIdx.x * blockDim.x + threadIdx.x;   // one thread = one 8-elem frag
  if (t >= WP_TOTAL / 8) return;
  int base = t * 8;
  us8 out;
  if (base >= W0P_ELEMS + 2 * W1P_ELEMS) {         // W3 region (A-frag, padded)
    int rem   = base - (W0P_ELEMS + 2 * W1P_ELEMS);
    int lane  = (rem >> 3) & 63;
    int kstep = rem >> 9;
    int k0    = kstep * 16 + (lane >> 5) * 8;
#pragma unroll
    for (int i = 0; i < 8; ++i)
      out[i] = ((lane & 31) == 0) ? f2bf(W3[k0 + i]) : (unsigned short)0;
  } else {
    const float* W; int rem, K;
    if (base < W0P_ELEMS)                  { W = W0; rem = base;                 K = 31;  }
    else if (base < W0P_ELEMS + W1P_ELEMS) { W = W1; rem = base - W0P_ELEMS;     K = 256; }
    else                                   { W = W2; rem = base - W0P_ELEMS - W1P_ELEMS; K = 256; }
    int lane  = (rem >> 3) & 63;
    int ct    = (rem >> 9) & 7;
    int kstep = rem >> 12;
    int j  = ct * 32 + (lane & 31);
    int k0 = kstep * 16 + (lane >> 5) * 8;
#pragma unroll
    for (int i = 0; i < 8; ++i) {
      int k = k0 + i;
      out[i] = (k < K) ? f2bf(W[k * 256 + j]) : (unsigned short)0;
    }
  }
  *reinterpret_cast<us8*>(wp + base) = out;
}

// ---------------- fused MLP + CC-reduction kernel (32x32x16 MFMA) ----------
// R16 shell (4 waves/block, 64 act rows = 63 real + pad, ping-pong ldsA/ldsB,
// bias-in-acc, weight dbuf w/ distance-2 macro prefetch, setprio, fused CC
// tail) re-tiled on v_mfma_f32_32x32x16_bf16: wave = 2 row-tiles x 2 col-tiles
// of 32x32, acc = 4 x fx16 = 64 VGPR (same as before), 8 MFMA per K=32
// macro-step (vs 16 at 16x16) at 4060 vs 3380 FLOP/cyc. Load counts per
// macro-step are IDENTICAL to R12/R16 (4 act ds_read_b128 + 4 weight b128).
// C/D layout (measured m74/m101): col(act row)=lane&31,
// neuron=(reg&3)+8*(reg>>2)+4*(lane>>5).

#define AOFF32(M, KS) (((unsigned)((M) * 512 + (KS) * 32 + hi * 16)) ^ ((unsigned)(((M) & 15) << 4)))

// macro step KT covers ksteps 2KT (S0,S1 = ct0,ct1) and 2KT+1 (S2,S3)
#define LOADW4(S0,S1,S2,S3, WB, KT)                                              \
  S0 = *reinterpret_cast<const bf8*>((WB) + (((2*(KT)  ) * 8 + cgrp * 2 + 0) * 64 + lane) * 8); \
  S1 = *reinterpret_cast<const bf8*>((WB) + (((2*(KT)  ) * 8 + cgrp * 2 + 1) * 64 + lane) * 8); \
  S2 = *reinterpret_cast<const bf8*>((WB) + (((2*(KT)+1) * 8 + cgrp * 2 + 0) * 64 + lane) * 8); \
  S3 = *reinterpret_cast<const bf8*>((WB) + (((2*(KT)+1) * 8 + cgrp * 2 + 1) * 64 + lane) * 8);

#define KSTEP(SRC, W00,W01,W10,W11, KT)                                          \
  {                                                                              \
    bf8 a00 = *reinterpret_cast<const bf8*>((SRC) + AOFF32(     l31, 2*(KT)  )); \
    bf8 a10 = *reinterpret_cast<const bf8*>((SRC) + AOFF32(32 + l31, 2*(KT)  )); \
    bf8 a01 = *reinterpret_cast<const bf8*>((SRC) + AOFF32(     l31, 2*(KT)+1)); \
    bf8 a11 = *reinterpret_cast<const bf8*>((SRC) + AOFF32(32 + l31, 2*(KT)+1)); \
    __builtin_amdgcn_s_setprio(1);                                               \
    cA = __builtin_amdgcn_mfma_f32_32x32x16_bf16(W00, a00, cA, 0, 0, 0);         \
    cB = __builtin_amdgcn_mfma_f32_32x32x16_bf16(W01, a00, cB, 0, 0, 0);         \
    cC = __builtin_amdgcn_mfma_f32_32x32x16_bf16(W00, a10, cC, 0, 0, 0);         \
    cD = __builtin_amdgcn_mfma_f32_32x32x16_bf16(W01, a10, cD, 0, 0, 0);         \
    cA = __builtin_amdgcn_mfma_f32_32x32x16_bf16(W10, a01, cA, 0, 0, 0);         \
    cB = __builtin_amdgcn_mfma_f32_32x32x16_bf16(W11, a01, cB, 0, 0, 0);         \
    cC = __builtin_amdgcn_mfma_f32_32x32x16_bf16(W10, a11, cC, 0, 0, 0);         \
    cD = __builtin_amdgcn_mfma_f32_32x32x16_bf16(W11, a11, cD, 0, 0, 0);         \
    __builtin_amdgcn_s_setprio(0);                                               \
  }

// 8 K=32 macro-steps, slots alternate, prefetch KT+2, tail loads next layer
#define DENSE_PIPE(SRC, WB, NWB)                                                 \
  KSTEP(SRC, wa0,wa1,wa2,wa3, 0) LOADW4(wa0,wa1,wa2,wa3, WB, 2)                  \
  KSTEP(SRC, wb0,wb1,wb2,wb3, 1) LOADW4(wb0,wb1,wb2,wb3, WB, 3)                  \
  KSTEP(SRC, wa0,wa1,wa2,wa3, 2) LOADW4(wa0,wa1,wa2,wa3, WB, 4)                  \
  KSTEP(SRC, wb0,wb1,wb2,wb3, 3) LOADW4(wb0,wb1,wb2,wb3, WB, 5)                  \
  KSTEP(SRC, wa0,wa1,wa2,wa3, 4) LOADW4(wa0,wa1,wa2,wa3, WB, 6)                  \
  KSTEP(SRC, wb0,wb1,wb2,wb3, 5) LOADW4(wb0,wb1,wb2,wb3, WB, 7)                  \
  KSTEP(SRC, wa0,wa1,wa2,wa3, 6) LOADW4(wa0,wa1,wa2,wa3, NWB, 0)                 \
  KSTEP(SRC, wb0,wb1,wb2,wb3, 7) LOADW4(wb0,wb1,wb2,wb3, NWB, 1)

#define DENSE_LAST(SRC, WB)                                                      \
  KSTEP(SRC, wa0,wa1,wa2,wa3, 0) LOADW4(wa0,wa1,wa2,wa3, WB, 2)                  \
  KSTEP(SRC, wb0,wb1,wb2,wb3, 1) LOADW4(wb0,wb1,wb2,wb3, WB, 3)                  \
  KSTEP(SRC, wa0,wa1,wa2,wa3, 2) LOADW4(wa0,wa1,wa2,wa3, WB, 4)                  \
  KSTEP(SRC, wb0,wb1,wb2,wb3, 3) LOADW4(wb0,wb1,wb2,wb3, WB, 5)                  \
  KSTEP(SRC, wa0,wa1,wa2,wa3, 4) LOADW4(wa0,wa1,wa2,wa3, WB, 6)                  \
  KSTEP(SRC, wb0,wb1,wb2,wb3, 5) LOADW4(wb0,wb1,wb2,wb3, WB, 7)                  \
  KSTEP(SRC, wa0,wa1,wa2,wa3, 6)                                                 \
  KSTEP(SRC, wb0,wb1,wb2,wb3, 7)

// bias into fx16 accumulator: neuron n(reg) = N0 + (reg>>2)*8 + hi*4 + (reg&3)
#define ACC_BIAS1(ACC, BIAS, N0)                                                 \
  {                                                                              \
    float4 t0 = *reinterpret_cast<const float4*>((BIAS) + (N0) + 0 * 8 + hi * 4);\
    float4 t1 = *reinterpret_cast<const float4*>((BIAS) + (N0) + 1 * 8 + hi * 4);\
    float4 t2 = *reinterpret_cast<const float4*>((BIAS) + (N0) + 2 * 8 + hi * 4);\
    float4 t3 = *reinterpret_cast<const float4*>((BIAS) + (N0) + 3 * 8 + hi * 4);\
    ACC = fx16{t0.x,t0.y,t0.z,t0.w, t1.x,t1.y,t1.z,t1.w,                         \
               t2.x,t2.y,t2.z,t2.w, t3.x,t3.y,t3.z,t3.w};                        \
  }
#define ACC_BIAS(BIAS)                                                           \
  ACC_BIAS1(cA, BIAS, cgrp * 64 + 0)                                             \
  ACC_BIAS1(cB, BIAS, cgrp * 64 + 32)                                            \
  cC = cA; cD = cB;

// ReLU + bf16-pack + ds_write_b64 of one fx16 tile (rows RT*32+l31)
#define STORE1(DST, ACC, RT, CT)                                                 \
  {                                                                              \
    int m = (RT) * 32 + l31;                                                     \
    unsigned int sbase = (unsigned int)(m * 512);                                \
    unsigned int swz   = (unsigned int)((m & 15) << 4);                          \
    _Pragma("unroll")                                                            \
    for (int q = 0; q < 4; ++q) {                                                \
      int n0 = cgrp * 64 + (CT) * 32 + q * 8 + hi * 4;                           \
      float v0 = fmaxf(ACC[4*q+0], 0.f);                                         \
      float v1 = fmaxf(ACC[4*q+1], 0.f);                                         \
      float v2 = fmaxf(ACC[4*q+2], 0.f);                                         \
      float v3 = fmaxf(ACC[4*q+3], 0.f);                                         \
      unsigned int p0, p1;                                                       \
      asm("v_cvt_pk_bf16_f32 %0, %1, %2" : "=v"(p0) : "v"(v0), "v"(v1));         \
      asm("v_cvt_pk_bf16_f32 %0, %1, %2" : "=v"(p1) : "v"(v2), "v"(v3));         \
      uint2 pk; pk.x = p0; pk.y = p1;                                            \
      *reinterpret_cast<uint2*>((DST) + ((sbase + (unsigned int)(n0 * 2)) ^ swz)) = pk; \
    }                                                                            \
  }
#define ACT_STORE(DST)                                                           \
  STORE1(DST, cA, 0, 0) STORE1(DST, cB, 0, 1)                                    \
  STORE1(DST, cC, 1, 0) STORE1(DST, cD, 1, 1)

__global__ __launch_bounds__(256, 1)
void mlp_kernel(const float* __restrict__ x, const float* __restrict__ h,
                const float* __restrict__ b0, const float* __restrict__ b1,
                const float* __restrict__ b2, const float* __restrict__ b3,
                const unsigned short* __restrict__ wp,
                const float* __restrict__ ccw,
                float* __restrict__ out) {
  __shared__ __align__(16) unsigned char ldsA[64 * 512];     // 32 KiB
  __shared__ __align__(16) unsigned char ldsB[64 * 512];     // 32 KiB
  __shared__ float ldsF[64];
  unsigned char* ldsIn = ldsB;         // layer-0 input overlays ldsB[0:4K]

  int tid  = threadIdx.x;
  int wv   = tid >> 6;
  int lane = tid & 63;
  int cgrp = wv;                 // 0..3 : 64-neuron group; wave owns all 64 rows
  int l31  = lane & 31;
  int hi   = lane >> 5;
  int blkbd = blockIdx.x * BDPB;

  const unsigned short* wb1p = wp + W0P_ELEMS;
  const unsigned short* wb2p = wp + W0P_ELEMS + W1P_ELEMS;
  const unsigned short* w3p  = wp + W0P_ELEMS + 2 * W1P_ELEMS;

  bf8 wa0, wa1, wa2, wa3, wb0, wb1, wb2, wb3;
  // layer-0 weights (one K=32 macro step) into slot A, before input staging
  LOADW4(wa0, wa1, wa2, wa3, wp, 0);

  // ---- stage layer-0 input: 63 real rows (3 bd x 21 s) + 1 zero pad row ----
  {
    int r = tid >> 2;                   // 0..63 (row within block)
    int q = tid & 3;                    // 8-col chunk
    unsigned int u = (unsigned int)r / NS;       // 0..2 (r=63 -> u=3)
    int s = r - (int)u * NS;
    int bd = blkbd + (int)u;
    us8 au = us8{0,0,0,0,0,0,0,0};
    if (r < 63 && bd < NBD) {
      float xv = x[bd];
      float node = xv * (cosf((float)s * 0.15707963267948966f) + 1.0f) * 0.5f;
      const float* hrow = h + bd * NCOND;
#pragma unroll
      for (int i = 0; i < 8; ++i) {
        int c = q * 8 + i;
        float v;
        if (c == 0)       v = node;
        else if (c <= 30) v = hrow[c - 1];
        else              v = 0.0f;
        au[i] = f2bf(v);
      }
    }
    unsigned int off = (unsigned int)(r * 64 + q * 16) ^ (unsigned int)((r & 3) << 4);
    *reinterpret_cast<us8*>(ldsIn + off) = au;
  }
  __syncthreads();

  fx16 cA, cB, cC, cD;

  // ======== layer 0: K=32 (2 ksteps), read ldsIn(B), store ldsA ========
  {
    ACC_BIAS(b0);
#pragma unroll
    for (int ks = 0; ks < 2; ++ks) {
      bf8 a0, a1;
      {
        int m0 = l31, m1 = 32 + l31;
        unsigned int o0 = (unsigned int)(m0 * 64 + ks * 32 + hi * 16) ^ (unsigned int)((m0 & 3) << 4);
        unsigned int o1 = (unsigned int)(m1 * 64 + ks * 32 + hi * 16) ^ (unsigned int)((m1 & 3) << 4);
        a0 = *reinterpret_cast<const bf8*>(ldsIn + o0);
        a1 = *reinterpret_cast<const bf8*>(ldsIn + o1);
      }
      if (ks == 0) {
        cA = __builtin_amdgcn_mfma_f32_32x32x16_bf16(wa0, a0, cA, 0, 0, 0);
        cB = __builtin_amdgcn_mfma_f32_32x32x16_bf16(wa1, a0, cB, 0, 0, 0);
        cC = __builtin_amdgcn_mfma_f32_32x32x16_bf16(wa0, a1, cC, 0, 0, 0);
        cD = __builtin_amdgcn_mfma_f32_32x32x16_bf16(wa1, a1, cD, 0, 0, 0);
      } else {
        cA = __builtin_amdgcn_mfma_f32_32x32x16_bf16(wa2, a0, cA, 0, 0, 0);
        cB = __builtin_amdgcn_mfma_f32_32x32x16_bf16(wa3, a0, cB, 0, 0, 0);
        cC = __builtin_amdgcn_mfma_f32_32x32x16_bf16(wa2, a1, cC, 0, 0, 0);
        cD = __builtin_amdgcn_mfma_f32_32x32x16_bf16(wa3, a1, cD, 0, 0, 0);
      }
    }
    // prefetch layer-1 macro-steps 0/1; loads straddle the store + barrier
    LOADW4(wa0, wa1, wa2, wa3, wb1p, 0);
    LOADW4(wb0, wb1, wb2, wb3, wb1p, 1);
    ACT_STORE(ldsA);                    // different buffer: no barrier needed
  }
  __syncthreads();

  // ======== layer 1: read ldsA, store ldsB (one barrier after stores) ========
  ACC_BIAS(b1);
  DENSE_PIPE(ldsA, wb1p, wb2p);          // tail prefetches layer-2 macro 0/1
  ACT_STORE(ldsB);
  __syncthreads();

  // ======== layer 2: read ldsB, store ldsA ========
  ACC_BIAS(b2);
  DENSE_LAST(ldsB, wb2p);
  ACT_STORE(ldsA);
  __syncthreads();

  // ======== layer 3: 256 -> 1 via MFMA; waves 0/1 take row-tile wv ========
  if (wv < 2) {
    fx16 a3 = fx16{0.f,0.f,0.f,0.f, 0.f,0.f,0.f,0.f, 0.f,0.f,0.f,0.f, 0.f,0.f,0.f,0.f};
    int m = wv * 32 + l31;
#pragma unroll
    for (int ks = 0; ks < 16; ++ks) {
      bf8 w3f = *reinterpret_cast<const bf8*>(w3p + (ks * 64 + lane) * 8);
      bf8 a = *reinterpret_cast<const bf8*>(ldsA + AOFF32(m, ks));
      a3 = __builtin_amdgcn_mfma_f32_32x32x16_bf16(w3f, a, a3, 0, 0, 0);
    }
    // neuron 0 lives in reg 0 of lanes with hi==0; act row = lane&31
    if (lane < 32) {
      float y = a3[0] + b3[0];
      float f = (y > 0.f) ? (y + 1.f) : expf(y);   // elu(y)+1
      ldsF[wv * 32 + lane] = f;
    }
  }
  __syncthreads();

  // ======== fused Clenshaw-Curtis reduction: 3 threads, one bd each ========
  if (tid < BDPB) {
    int bd = blkbd + tid;
    if (bd < NBD) {
      float acc2 = 0.f;
#pragma unroll
      for (int s2 = 0; s2 < NS; ++s2) acc2 += ldsF[tid * NS + s2] * ccw[s2];
      out[bd] = acc2 * x[bd] * 0.5f + h[bd * NCOND];  // z = z_est + h[:,:,0]
      out[NBD + bd] = ldsF[tid * NS];                 // jac = f at s=0
    }
  }
}

// ---------------- launcher ----------------
extern "C" void kernel_launch(void* const* d_in, const int* in_sizes, int n_in,
                              void* d_out, int out_size, void* d_ws, size_t ws_size,
                              hipStream_t stream) {
  (void)in_sizes; (void)n_in; (void)out_size; (void)ws_size;
  const float* x  = (const float*)d_in[0];
  const float* h  = (const float*)d_in[1];
  const float* W0 = (const float*)d_in[2];
  const float* b0 = (const float*)d_in[3];
  const float* W1 = (const float*)d_in[4];
  const float* b1 = (const float*)d_in[5];
  const float* W2 = (const float*)d_in[6];
  const float* b2 = (const float*)d_in[7];
  const float* W3 = (const float*)d_in[8];
  const float* b3 = (const float*)d_in[9];

  unsigned short* wp = (unsigned short*)d_ws;
  float* ccwbuf = (float*)((char*)d_ws + WP_TOTAL * sizeof(unsigned short));
  float* out  = (float*)d_out;

  prep_pack<<<(WP_TOTAL / 8 + 255) / 256, 256, 0, stream>>>(W0, W1, W2, W3, wp, ccwbuf);
  mlp_kernel<<<NBLK, 256, 0, stream>>>(x, h, b0, b1, b2, b3, wp, ccwbuf, out);
}

// Round 18
// 106.079 us; speedup vs baseline: 1.5502x; 1.5502x over previous
//
#include <hip/hip_runtime.h>
#include <math.h>

// ---------------- problem constants ----------------
#define NB        512
#define ND        32
#define NCOND     30
#define NS        21                  // NB_STEPS+1 quadrature nodes
#define NBD       (NB*ND)             // 16384
#define BDPB      3                   // bd-groups per block (63 rows + 1 pad)
#define NBLK      ((NBD + BDPB - 1) / BDPB)   // 5462 blocks

// packed-weight element counts (ushort)
#define W0P_ELEMS (1*16*64*8)         // 8192
#define W1P_ELEMS (8*16*64*8)         // 65536
#define W3P_ELEMS (8*64*8)            // 4096  (zero-padded W3 as A-fragments)
#define WP_TOTAL  (W0P_ELEMS + 2*W1P_ELEMS + W3P_ELEMS)  // 143360

typedef __bf16 bf8 __attribute__((ext_vector_type(8)));
typedef float  fx4 __attribute__((ext_vector_type(4)));
typedef unsigned short us8 __attribute__((ext_vector_type(8)));

__device__ __forceinline__ unsigned short f2bf(float f) {
  unsigned int u = __float_as_uint(f);
  u += 0x7FFFu + ((u >> 16) & 1u);        // round-to-nearest-even
  return (unsigned short)(u >> 16);
}

// ---------------- kernel 1: pack weights + Clenshaw-Curtis weights ----------
__global__ void prep_pack(const float* __restrict__ W0,
                          const float* __restrict__ W1,
                          const float* __restrict__ W2,
                          const float* __restrict__ W3,
                          unsigned short* __restrict__ wp,
                          float* __restrict__ ccwbuf) {
  if (blockIdx.x == 0 && threadIdx.x < NS) {   // cc weights (double prec, once)
    int tid = threadIdx.x;
    double acc = 0.0;
#pragma unroll
    for (int i = 0; i <= 20; i += 2) {
      double wi = (i == 0) ? 1.0 : 2.0 / (1.0 - (double)(i * i));
      acc += cos((double)(i * tid) * 3.141592653589793 / 20.0) * wi;
    }
    double edge = (tid == 0 || tid == 20) ? 0.5 : 1.0;
    ccwbuf[tid] = (float)(acc * 0.1 * edge);
  }
  int t = blockIdx.x * blockDim.x + threadIdx.x;   // one thread = one 8-elem frag
  if (t >= WP_TOTAL / 8) return;
  int base = t * 8;
  us8 out;
  if (base >= W0P_ELEMS + 2 * W1P_ELEMS) {         // W3 region
    int rem  = base - (W0P_ELEMS + 2 * W1P_ELEMS);
    int lane = (rem >> 3) & 63;
    int ktl  = rem >> 9;
    int k0   = ktl * 32 + (lane >> 4) * 8;
#pragma unroll
    for (int i = 0; i < 8; ++i)
      out[i] = ((lane & 15) == 0) ? f2bf(W3[k0 + i]) : (unsigned short)0;
  } else {
    const float* W; int rem, K;
    if (base < W0P_ELEMS)                  { W = W0; rem = base;                 K = 31;  }
    else if (base < W0P_ELEMS + W1P_ELEMS) { W = W1; rem = base - W0P_ELEMS;     K = 256; }
    else                                   { W = W2; rem = base - W0P_ELEMS - W1P_ELEMS; K = 256; }
    int lane = (rem >> 3) & 63;
    int ct   = (rem >> 9) & 15;
    int ktl  =  rem >> 13;
    int j  = ct * 16 + (lane & 15);
    int k0 = ktl * 32 + (lane >> 4) * 8;
#pragma unroll
    for (int i = 0; i < 8; ++i) {
      int k = k0 + i;
      out[i] = (k < K) ? f2bf(W[k * 256 + j]) : (unsigned short)0;
    }
  }
  *reinterpret_cast<us8*>(wp + base) = out;
}

// ---------------- fused MLP + CC-reduction kernel ----------------
// R16 champion restored verbatim (4 waves/block, 64 act rows = 63 real + pad,
// wave = 4rt x 4ct 16x16x32 MFMA, ping-pong ldsA/ldsB, bias-in-acc, weight
// dbuf, fused CC tail, (256,2)) MINUS the s_setprio pair: m190-style A/B —
// setprio helps phase-split schedules only and measured -1.5% on
// barrier-lockstep GEMM, which is this structure.

#define ACC_BIAS(BIAS)                                                           \
  {                                                                              \
    float4 bq0 = *reinterpret_cast<const float4*>((BIAS) + (cgrp * 4 + 0) * 16 + khalf * 4); \
    float4 bq1 = *reinterpret_cast<const float4*>((BIAS) + (cgrp * 4 + 1) * 16 + khalf * 4); \
    float4 bq2 = *reinterpret_cast<const float4*>((BIAS) + (cgrp * 4 + 2) * 16 + khalf * 4); \
    float4 bq3 = *reinterpret_cast<const float4*>((BIAS) + (cgrp * 4 + 3) * 16 + khalf * 4); \
    _Pragma("unroll")                                                            \
    for (int rt = 0; rt < 4; ++rt) {                                             \
      acc[rt][0] = fx4{bq0.x, bq0.y, bq0.z, bq0.w};                              \
      acc[rt][1] = fx4{bq1.x, bq1.y, bq1.z, bq1.w};                              \
      acc[rt][2] = fx4{bq2.x, bq2.y, bq2.z, bq2.w};                              \
      acc[rt][3] = fx4{bq3.x, bq3.y, bq3.z, bq3.w};                              \
    }                                                                            \
  }

#define LOADW4(S0,S1,S2,S3, WB, KT)                                              \
  S0 = *reinterpret_cast<const bf8*>((WB) + (((KT) * 16 + cgrp * 4 + 0) * 64 + lane) * 8); \
  S1 = *reinterpret_cast<const bf8*>((WB) + (((KT) * 16 + cgrp * 4 + 1) * 64 + lane) * 8); \
  S2 = *reinterpret_cast<const bf8*>((WB) + (((KT) * 16 + cgrp * 4 + 2) * 64 + lane) * 8); \
  S3 = *reinterpret_cast<const bf8*>((WB) + (((KT) * 16 + cgrp * 4 + 3) * 64 + lane) * 8);

#define AOFF(M, KT) (((unsigned)((M) * 512 + (KT) * 64 + khalf * 16)) ^ ((unsigned)(((M) & 15) << 4)))

#define KSTEP(SRC, W0_,W1_,W2_,W3_, KT)                                          \
  {                                                                              \
    bf8 a0 = *reinterpret_cast<const bf8*>((SRC) + AOFF( 0 + colb, KT));         \
    bf8 a1 = *reinterpret_cast<const bf8*>((SRC) + AOFF(16 + colb, KT));         \
    bf8 a2 = *reinterpret_cast<const bf8*>((SRC) + AOFF(32 + colb, KT));         \
    bf8 a3 = *reinterpret_cast<const bf8*>((SRC) + AOFF(48 + colb, KT));         \
    acc[0][0] = __builtin_amdgcn_mfma_f32_16x16x32_bf16(W0_, a0, acc[0][0], 0, 0, 0); \
    acc[0][1] = __builtin_amdgcn_mfma_f32_16x16x32_bf16(W1_, a0, acc[0][1], 0, 0, 0); \
    acc[0][2] = __builtin_amdgcn_mfma_f32_16x16x32_bf16(W2_, a0, acc[0][2], 0, 0, 0); \
    acc[0][3] = __builtin_amdgcn_mfma_f32_16x16x32_bf16(W3_, a0, acc[0][3], 0, 0, 0); \
    acc[1][0] = __builtin_amdgcn_mfma_f32_16x16x32_bf16(W0_, a1, acc[1][0], 0, 0, 0); \
    acc[1][1] = __builtin_amdgcn_mfma_f32_16x16x32_bf16(W1_, a1, acc[1][1], 0, 0, 0); \
    acc[1][2] = __builtin_amdgcn_mfma_f32_16x16x32_bf16(W2_, a1, acc[1][2], 0, 0, 0); \
    acc[1][3] = __builtin_amdgcn_mfma_f32_16x16x32_bf16(W3_, a1, acc[1][3], 0, 0, 0); \
    acc[2][0] = __builtin_amdgcn_mfma_f32_16x16x32_bf16(W0_, a2, acc[2][0], 0, 0, 0); \
    acc[2][1] = __builtin_amdgcn_mfma_f32_16x16x32_bf16(W1_, a2, acc[2][1], 0, 0, 0); \
    acc[2][2] = __builtin_amdgcn_mfma_f32_16x16x32_bf16(W2_, a2, acc[2][2], 0, 0, 0); \
    acc[2][3] = __builtin_amdgcn_mfma_f32_16x16x32_bf16(W3_, a2, acc[2][3], 0, 0, 0); \
    acc[3][0] = __builtin_amdgcn_mfma_f32_16x16x32_bf16(W0_, a3, acc[3][0], 0, 0, 0); \
    acc[3][1] = __builtin_amdgcn_mfma_f32_16x16x32_bf16(W1_, a3, acc[3][1], 0, 0, 0); \
    acc[3][2] = __builtin_amdgcn_mfma_f32_16x16x32_bf16(W2_, a3, acc[3][2], 0, 0, 0); \
    acc[3][3] = __builtin_amdgcn_mfma_f32_16x16x32_bf16(W3_, a3, acc[3][3], 0, 0, 0); \
  }

// K-steps 0..7, consuming alternating slots, prefetching kt+2 (then next layer)
#define DENSE_PIPE(SRC, WB, NWB)                                                 \
  KSTEP(SRC, wa0,wa1,wa2,wa3, 0) LOADW4(wa0,wa1,wa2,wa3, WB, 2)                  \
  KSTEP(SRC, wb0,wb1,wb2,wb3, 1) LOADW4(wb0,wb1,wb2,wb3, WB, 3)                  \
  KSTEP(SRC, wa0,wa1,wa2,wa3, 2) LOADW4(wa0,wa1,wa2,wa3, WB, 4)                  \
  KSTEP(SRC, wb0,wb1,wb2,wb3, 3) LOADW4(wb0,wb1,wb2,wb3, WB, 5)                  \
  KSTEP(SRC, wa0,wa1,wa2,wa3, 4) LOADW4(wa0,wa1,wa2,wa3, WB, 6)                  \
  KSTEP(SRC, wb0,wb1,wb2,wb3, 5) LOADW4(wb0,wb1,wb2,wb3, WB, 7)                  \
  KSTEP(SRC, wa0,wa1,wa2,wa3, 6) LOADW4(wa0,wa1,wa2,wa3, NWB, 0)                 \
  KSTEP(SRC, wb0,wb1,wb2,wb3, 7) LOADW4(wb0,wb1,wb2,wb3, NWB, 1)

#define DENSE_LAST(SRC, WB)                                                      \
  KSTEP(SRC, wa0,wa1,wa2,wa3, 0) LOADW4(wa0,wa1,wa2,wa3, WB, 2)                  \
  KSTEP(SRC, wb0,wb1,wb2,wb3, 1) LOADW4(wb0,wb1,wb2,wb3, WB, 3)                  \
  KSTEP(SRC, wa0,wa1,wa2,wa3, 2) LOADW4(wa0,wa1,wa2,wa3, WB, 4)                  \
  KSTEP(SRC, wb0,wb1,wb2,wb3, 3) LOADW4(wb0,wb1,wb2,wb3, WB, 5)                  \
  KSTEP(SRC, wa0,wa1,wa2,wa3, 4) LOADW4(wa0,wa1,wa2,wa3, WB, 6)                  \
  KSTEP(SRC, wb0,wb1,wb2,wb3, 5) LOADW4(wb0,wb1,wb2,wb3, WB, 7)                  \
  KSTEP(SRC, wa0,wa1,wa2,wa3, 6)                                                 \
  KSTEP(SRC, wb0,wb1,wb2,wb3, 7)

// ReLU + bf16-pack + ds_write_b64 store of acc into DST (bias already in acc)
#define ACT_STORE(DST)                                                           \
  {                                                                              \
    _Pragma("unroll")                                                            \
    for (int rt = 0; rt < 4; ++rt) {                                             \
      int m = rt * 16 + colb;                                                    \
      unsigned int sbase = (unsigned int)(m * 512);                              \
      unsigned int swz   = (unsigned int)((m & 15) << 4);                        \
      _Pragma("unroll")                                                          \
      for (int ct = 0; ct < 4; ++ct) {                                           \
        int n0 = (cgrp * 4 + ct) * 16 + khalf * 4;                               \
        float v0 = fmaxf(acc[rt][ct][0], 0.f);                                   \
        float v1 = fmaxf(acc[rt][ct][1], 0.f);                                   \
        float v2 = fmaxf(acc[rt][ct][2], 0.f);                                   \
        float v3 = fmaxf(acc[rt][ct][3], 0.f);                                   \
        unsigned int p0, p1;                                                     \
        asm("v_cvt_pk_bf16_f32 %0, %1, %2" : "=v"(p0) : "v"(v0), "v"(v1));       \
        asm("v_cvt_pk_bf16_f32 %0, %1, %2" : "=v"(p1) : "v"(v2), "v"(v3));       \
        uint2 pk; pk.x = p0; pk.y = p1;                                          \
        *reinterpret_cast<uint2*>((DST) + ((sbase + (unsigned int)(n0 * 2)) ^ swz)) = pk; \
      }                                                                          \
    }                                                                            \
  }

__global__ __launch_bounds__(256, 2)
void mlp_kernel(const float* __restrict__ x, const float* __restrict__ h,
                const float* __restrict__ b0, const float* __restrict__ b1,
                const float* __restrict__ b2, const float* __restrict__ b3,
                const unsigned short* __restrict__ wp,
                const float* __restrict__ ccw,
                float* __restrict__ out) {
  __shared__ __align__(16) unsigned char ldsA[64 * 512];     // 32 KiB
  __shared__ __align__(16) unsigned char ldsB[64 * 512];     // 32 KiB
  __shared__ float ldsF[64];
  unsigned char* ldsIn = ldsB;         // layer-0 input overlays ldsB[0:4K]

  int tid  = threadIdx.x;
  int wv   = tid >> 6;
  int lane = tid & 63;
  int cgrp = wv;                 // 0..3 : 64-neuron group; wave owns all 64 rows
  int colb  = lane & 15;
  int khalf = lane >> 4;
  int blkbd = blockIdx.x * BDPB;

  const unsigned short* wb1p = wp + W0P_ELEMS;
  const unsigned short* wb2p = wp + W0P_ELEMS + W1P_ELEMS;
  const unsigned short* w3p  = wp + W0P_ELEMS + 2 * W1P_ELEMS;

  bf8 wa0, wa1, wa2, wa3, wb0, wb1, wb2, wb3;
  // layer-0 weights (single K-step) into slot A, issued before input staging
  LOADW4(wa0, wa1, wa2, wa3, wp, 0);

  // ---- stage layer-0 input: 63 real rows (3 bd x 21 s) + 1 zero pad row ----
  {
    int r = tid >> 2;                   // 0..63 (row within block)
    int q = tid & 3;                    // 8-col chunk
    unsigned int u = (unsigned int)r / NS;       // 0..2 (r=63 -> u=3)
    int s = r - (int)u * NS;
    int bd = blkbd + (int)u;
    us8 au = us8{0,0,0,0,0,0,0,0};
    if (r < 63 && bd < NBD) {
      float xv = x[bd];
      float node = xv * (cosf((float)s * 0.15707963267948966f) + 1.0f) * 0.5f;
      const float* hrow = h + bd * NCOND;
#pragma unroll
      for (int i = 0; i < 8; ++i) {
        int c = q * 8 + i;
        float v;
        if (c == 0)       v = node;
        else if (c <= 30) v = hrow[c - 1];
        else              v = 0.0f;
        au[i] = f2bf(v);
      }
    }
    unsigned int off = (unsigned int)(r * 64 + q * 16) ^ (unsigned int)((r & 3) << 4);
    *reinterpret_cast<us8*>(ldsIn + off) = au;
  }
  __syncthreads();

  fx4 acc[4][4];

  // ======== layer 0: K=32, read ldsIn(B), store ldsA — no mid barrier ========
  {
    ACC_BIAS(b0);
#pragma unroll
    for (int rt = 0; rt < 4; ++rt) {
      int m = rt * 16 + colb;
      unsigned int off = (unsigned int)(m * 64 + khalf * 16) ^ (unsigned int)((m & 3) << 4);
      bf8 a = *reinterpret_cast<const bf8*>(ldsIn + off);
      acc[rt][0] = __builtin_amdgcn_mfma_f32_16x16x32_bf16(wa0, a, acc[rt][0], 0, 0, 0);
      acc[rt][1] = __builtin_amdgcn_mfma_f32_16x16x32_bf16(wa1, a, acc[rt][1], 0, 0, 0);
      acc[rt][2] = __builtin_amdgcn_mfma_f32_16x16x32_bf16(wa2, a, acc[rt][2], 0, 0, 0);
      acc[rt][3] = __builtin_amdgcn_mfma_f32_16x16x32_bf16(wa3, a, acc[rt][3], 0, 0, 0);
    }
    // prefetch layer-1 kt0/kt1; loads straddle the store + barrier
    LOADW4(wa0, wa1, wa2, wa3, wb1p, 0);
    LOADW4(wb0, wb1, wb2, wb3, wb1p, 1);
    ACT_STORE(ldsA);                    // different buffer: no barrier needed
  }
  __syncthreads();

  // ======== layer 1: read ldsA, store ldsB (one barrier after stores) ========
  ACC_BIAS(b1);
  DENSE_PIPE(ldsA, wb1p, wb2p);          // tail prefetches layer-2 kt0/kt1
  ACT_STORE(ldsB);
  __syncthreads();

  // ======== layer 2: read ldsB, store ldsA ========
  ACC_BIAS(b2);
  DENSE_LAST(ldsB, wb2p);
  ACT_STORE(ldsA);
  __syncthreads();

  // ======== layer 3: 256 -> 1 via MFMA, wave wv handles rows wv*16..wv*16+15 ==
  {
    fx4 a3 = fx4{0.f, 0.f, 0.f, 0.f};
    int m = wv * 16 + colb;
    unsigned int abase = (unsigned int)(m * 512 + khalf * 16);
    unsigned int aswz  = (unsigned int)((m & 15) << 4);
#pragma unroll
    for (int kt = 0; kt < 8; ++kt) {
      bf8 w3f = *reinterpret_cast<const bf8*>(w3p + (kt * 64 + lane) * 8);
      bf8 a = *reinterpret_cast<const bf8*>(ldsA + ((abase + (unsigned)(kt * 64)) ^ aswz));
      a3 = __builtin_amdgcn_mfma_f32_16x16x32_bf16(w3f, a, a3, 0, 0, 0);
    }
    if (lane < 16) {
      float y = a3[0] + b3[0];
      float f = (y > 0.f) ? (y + 1.f) : expf(y);   // elu(y)+1
      ldsF[wv * 16 + lane] = f;
    }
  }
  __syncthreads();

  // ======== fused Clenshaw-Curtis reduction: 3 threads, one bd each ========
  if (tid < BDPB) {
    int bd = blkbd + tid;
    if (bd < NBD) {
      float acc2 = 0.f;
#pragma unroll
      for (int s2 = 0; s2 < NS; ++s2) acc2 += ldsF[tid * NS + s2] * ccw[s2];
      out[bd] = acc2 * x[bd] * 0.5f + h[bd * NCOND];  // z = z_est + h[:,:,0]
      out[NBD + bd] = ldsF[tid * NS];                 // jac = f at s=0
    }
  }
}

// ---------------- launcher ----------------
extern "C" void kernel_launch(void* const* d_in, const int* in_sizes, int n_in,
                              void* d_out, int out_size, void* d_ws, size_t ws_size,
                              hipStream_t stream) {
  (void)in_sizes; (void)n_in; (void)out_size; (void)ws_size;
  const float* x  = (const float*)d_in[0];
  const float* h  = (const float*)d_in[1];
  const float* W0 = (const float*)d_in[2];
  const float* b0 = (const float*)d_in[3];
  const float* W1 = (const float*)d_in[4];
  const float* b1 = (const float*)d_in[5];
  const float* W2 = (const float*)d_in[6];
  const float* b2 = (const float*)d_in[7];
  const float* W3 = (const float*)d_in[8];
  const float* b3 = (const float*)d_in[9];

  unsigned short* wp = (unsigned short*)d_ws;
  float* ccwbuf = (float*)((char*)d_ws + WP_TOTAL * sizeof(unsigned short));
  float* out  = (float*)d_out;

  prep_pack<<<(WP_TOTAL / 8 + 255) / 256, 256, 0, stream>>>(W0, W1, W2, W3, wp, ccwbuf);
  mlp_kernel<<<NBLK, 256, 0, stream>>>(x, h, b0, b1, b2, b3, wp, ccwbuf, out);
}

// Round 19
// 101.046 us; speedup vs baseline: 1.6274x; 1.0498x over previous
//
#include <hip/hip_runtime.h>
#include <math.h>

// ---------------- problem constants ----------------
#define NB        512
#define ND        32
#define NCOND     30
#define NS        21                  // NB_STEPS+1 quadrature nodes
#define NBD       (NB*ND)             // 16384
#define BDPB      3                   // bd-groups per block (63 rows + 1 pad)
#define NBLK      ((NBD + BDPB - 1) / BDPB)   // 5462 blocks

// packed-weight element counts (ushort)
#define W0P_ELEMS (1*16*64*8)         // 8192
#define W1P_ELEMS (8*16*64*8)         // 65536
#define W3P_ELEMS (8*64*8)            // 4096  (zero-padded W3 as A-fragments)
#define WP_TOTAL  (W0P_ELEMS + 2*W1P_ELEMS + W3P_ELEMS)  // 143360

typedef __bf16 bf8 __attribute__((ext_vector_type(8)));
typedef float  fx4 __attribute__((ext_vector_type(4)));
typedef unsigned short us8 __attribute__((ext_vector_type(8)));

__device__ __forceinline__ unsigned short f2bf(float f) {
  unsigned int u = __float_as_uint(f);
  u += 0x7FFFu + ((u >> 16) & 1u);        // round-to-nearest-even
  return (unsigned short)(u >> 16);
}

// ---------------- kernel 1: pack weights + Clenshaw-Curtis weights ----------
__global__ void prep_pack(const float* __restrict__ W0,
                          const float* __restrict__ W1,
                          const float* __restrict__ W2,
                          const float* __restrict__ W3,
                          unsigned short* __restrict__ wp,
                          float* __restrict__ ccwbuf) {
  if (blockIdx.x == 0 && threadIdx.x < NS) {   // cc weights (double prec, once)
    int tid = threadIdx.x;
    double acc = 0.0;
#pragma unroll
    for (int i = 0; i <= 20; i += 2) {
      double wi = (i == 0) ? 1.0 : 2.0 / (1.0 - (double)(i * i));
      acc += cos((double)(i * tid) * 3.141592653589793 / 20.0) * wi;
    }
    double edge = (tid == 0 || tid == 20) ? 0.5 : 1.0;
    ccwbuf[tid] = (float)(acc * 0.1 * edge);
  }
  int t = blockIdx.x * blockDim.x + threadIdx.x;   // one thread = one 8-elem frag
  if (t >= WP_TOTAL / 8) return;
  int base = t * 8;
  us8 out;
  if (base >= W0P_ELEMS + 2 * W1P_ELEMS) {         // W3 region
    int rem  = base - (W0P_ELEMS + 2 * W1P_ELEMS);
    int lane = (rem >> 3) & 63;
    int ktl  = rem >> 9;
    int k0   = ktl * 32 + (lane >> 4) * 8;
#pragma unroll
    for (int i = 0; i < 8; ++i)
      out[i] = ((lane & 15) == 0) ? f2bf(W3[k0 + i]) : (unsigned short)0;
  } else {
    const float* W; int rem, K;
    if (base < W0P_ELEMS)                  { W = W0; rem = base;                 K = 31;  }
    else if (base < W0P_ELEMS + W1P_ELEMS) { W = W1; rem = base - W0P_ELEMS;     K = 256; }
    else                                   { W = W2; rem = base - W0P_ELEMS - W1P_ELEMS; K = 256; }
    int lane = (rem >> 3) & 63;
    int ct   = (rem >> 9) & 15;
    int ktl  =  rem >> 13;
    int j  = ct * 16 + (lane & 15);
    int k0 = ktl * 32 + (lane >> 4) * 8;
#pragma unroll
    for (int i = 0; i < 8; ++i) {
      int k = k0 + i;
      out[i] = (k < K) ? f2bf(W[k * 256 + j]) : (unsigned short)0;
    }
  }
  *reinterpret_cast<us8*>(wp + base) = out;
}

// ---------------- fused MLP + CC-reduction kernel ----------------
// R16 CHAMPION restored verbatim: 4 waves/block, 64 act rows (63 real + pad),
// wave = 4rt x 4ct 16x16x32 MFMA, ping-pong ldsA/ldsB (1 barrier/layer),
// bias-in-accumulator, depth-2 weight register pipeline with cross-barrier
// prefetch, s_setprio around MFMA bursts (R18 A/B: removal costs ~5% total —
// the 2 resident blocks/CU at uncorrelated phases provide the role diversity
// setprio arbitrates), fused CC reduction tail, launch_bounds(256,2).

#define ACC_BIAS(BIAS)                                                           \
  {                                                                              \
    float4 bq0 = *reinterpret_cast<const float4*>((BIAS) + (cgrp * 4 + 0) * 16 + khalf * 4); \
    float4 bq1 = *reinterpret_cast<const float4*>((BIAS) + (cgrp * 4 + 1) * 16 + khalf * 4); \
    float4 bq2 = *reinterpret_cast<const float4*>((BIAS) + (cgrp * 4 + 2) * 16 + khalf * 4); \
    float4 bq3 = *reinterpret_cast<const float4*>((BIAS) + (cgrp * 4 + 3) * 16 + khalf * 4); \
    _Pragma("unroll")                                                            \
    for (int rt = 0; rt < 4; ++rt) {                                             \
      acc[rt][0] = fx4{bq0.x, bq0.y, bq0.z, bq0.w};                              \
      acc[rt][1] = fx4{bq1.x, bq1.y, bq1.z, bq1.w};                              \
      acc[rt][2] = fx4{bq2.x, bq2.y, bq2.z, bq2.w};                              \
      acc[rt][3] = fx4{bq3.x, bq3.y, bq3.z, bq3.w};                              \
    }                                                                            \
  }

#define LOADW4(S0,S1,S2,S3, WB, KT)                                              \
  S0 = *reinterpret_cast<const bf8*>((WB) + (((KT) * 16 + cgrp * 4 + 0) * 64 + lane) * 8); \
  S1 = *reinterpret_cast<const bf8*>((WB) + (((KT) * 16 + cgrp * 4 + 1) * 64 + lane) * 8); \
  S2 = *reinterpret_cast<const bf8*>((WB) + (((KT) * 16 + cgrp * 4 + 2) * 64 + lane) * 8); \
  S3 = *reinterpret_cast<const bf8*>((WB) + (((KT) * 16 + cgrp * 4 + 3) * 64 + lane) * 8);

#define AOFF(M, KT) (((unsigned)((M) * 512 + (KT) * 64 + khalf * 16)) ^ ((unsigned)(((M) & 15) << 4)))

#define KSTEP(SRC, W0_,W1_,W2_,W3_, KT)                                          \
  {                                                                              \
    bf8 a0 = *reinterpret_cast<const bf8*>((SRC) + AOFF( 0 + colb, KT));         \
    bf8 a1 = *reinterpret_cast<const bf8*>((SRC) + AOFF(16 + colb, KT));         \
    bf8 a2 = *reinterpret_cast<const bf8*>((SRC) + AOFF(32 + colb, KT));         \
    bf8 a3 = *reinterpret_cast<const bf8*>((SRC) + AOFF(48 + colb, KT));         \
    __builtin_amdgcn_s_setprio(1);                                               \
    acc[0][0] = __builtin_amdgcn_mfma_f32_16x16x32_bf16(W0_, a0, acc[0][0], 0, 0, 0); \
    acc[0][1] = __builtin_amdgcn_mfma_f32_16x16x32_bf16(W1_, a0, acc[0][1], 0, 0, 0); \
    acc[0][2] = __builtin_amdgcn_mfma_f32_16x16x32_bf16(W2_, a0, acc[0][2], 0, 0, 0); \
    acc[0][3] = __builtin_amdgcn_mfma_f32_16x16x32_bf16(W3_, a0, acc[0][3], 0, 0, 0); \
    acc[1][0] = __builtin_amdgcn_mfma_f32_16x16x32_bf16(W0_, a1, acc[1][0], 0, 0, 0); \
    acc[1][1] = __builtin_amdgcn_mfma_f32_16x16x32_bf16(W1_, a1, acc[1][1], 0, 0, 0); \
    acc[1][2] = __builtin_amdgcn_mfma_f32_16x16x32_bf16(W2_, a1, acc[1][2], 0, 0, 0); \
    acc[1][3] = __builtin_amdgcn_mfma_f32_16x16x32_bf16(W3_, a1, acc[1][3], 0, 0, 0); \
    acc[2][0] = __builtin_amdgcn_mfma_f32_16x16x32_bf16(W0_, a2, acc[2][0], 0, 0, 0); \
    acc[2][1] = __builtin_amdgcn_mfma_f32_16x16x32_bf16(W1_, a2, acc[2][1], 0, 0, 0); \
    acc[2][2] = __builtin_amdgcn_mfma_f32_16x16x32_bf16(W2_, a2, acc[2][2], 0, 0, 0); \
    acc[2][3] = __builtin_amdgcn_mfma_f32_16x16x32_bf16(W3_, a2, acc[2][3], 0, 0, 0); \
    acc[3][0] = __builtin_amdgcn_mfma_f32_16x16x32_bf16(W0_, a3, acc[3][0], 0, 0, 0); \
    acc[3][1] = __builtin_amdgcn_mfma_f32_16x16x32_bf16(W1_, a3, acc[3][1], 0, 0, 0); \
    acc[3][2] = __builtin_amdgcn_mfma_f32_16x16x32_bf16(W2_, a3, acc[3][2], 0, 0, 0); \
    acc[3][3] = __builtin_amdgcn_mfma_f32_16x16x32_bf16(W3_, a3, acc[3][3], 0, 0, 0); \
    __builtin_amdgcn_s_setprio(0);                                               \
  }

// K-steps 0..7, consuming alternating slots, prefetching kt+2 (then next layer)
#define DENSE_PIPE(SRC, WB, NWB)                                                 \
  KSTEP(SRC, wa0,wa1,wa2,wa3, 0) LOADW4(wa0,wa1,wa2,wa3, WB, 2)                  \
  KSTEP(SRC, wb0,wb1,wb2,wb3, 1) LOADW4(wb0,wb1,wb2,wb3, WB, 3)                  \
  KSTEP(SRC, wa0,wa1,wa2,wa3, 2) LOADW4(wa0,wa1,wa2,wa3, WB, 4)                  \
  KSTEP(SRC, wb0,wb1,wb2,wb3, 3) LOADW4(wb0,wb1,wb2,wb3, WB, 5)                  \
  KSTEP(SRC, wa0,wa1,wa2,wa3, 4) LOADW4(wa0,wa1,wa2,wa3, WB, 6)                  \
  KSTEP(SRC, wb0,wb1,wb2,wb3, 5) LOADW4(wb0,wb1,wb2,wb3, WB, 7)                  \
  KSTEP(SRC, wa0,wa1,wa2,wa3, 6) LOADW4(wa0,wa1,wa2,wa3, NWB, 0)                 \
  KSTEP(SRC, wb0,wb1,wb2,wb3, 7) LOADW4(wb0,wb1,wb2,wb3, NWB, 1)

#define DENSE_LAST(SRC, WB)                                                      \
  KSTEP(SRC, wa0,wa1,wa2,wa3, 0) LOADW4(wa0,wa1,wa2,wa3, WB, 2)                  \
  KSTEP(SRC, wb0,wb1,wb2,wb3, 1) LOADW4(wb0,wb1,wb2,wb3, WB, 3)                  \
  KSTEP(SRC, wa0,wa1,wa2,wa3, 2) LOADW4(wa0,wa1,wa2,wa3, WB, 4)                  \
  KSTEP(SRC, wb0,wb1,wb2,wb3, 3) LOADW4(wb0,wb1,wb2,wb3, WB, 5)                  \
  KSTEP(SRC, wa0,wa1,wa2,wa3, 4) LOADW4(wa0,wa1,wa2,wa3, WB, 6)                  \
  KSTEP(SRC, wb0,wb1,wb2,wb3, 5) LOADW4(wb0,wb1,wb2,wb3, WB, 7)                  \
  KSTEP(SRC, wa0,wa1,wa2,wa3, 6)                                                 \
  KSTEP(SRC, wb0,wb1,wb2,wb3, 7)

// ReLU + bf16-pack + ds_write_b64 store of acc into DST (bias already in acc)
#define ACT_STORE(DST)                                                           \
  {                                                                              \
    _Pragma("unroll")                                                            \
    for (int rt = 0; rt < 4; ++rt) {                                             \
      int m = rt * 16 + colb;                                                    \
      unsigned int sbase = (unsigned int)(m * 512);                              \
      unsigned int swz   = (unsigned int)((m & 15) << 4);                        \
      _Pragma("unroll")                                                          \
      for (int ct = 0; ct < 4; ++ct) {                                           \
        int n0 = (cgrp * 4 + ct) * 16 + khalf * 4;                               \
        float v0 = fmaxf(acc[rt][ct][0], 0.f);                                   \
        float v1 = fmaxf(acc[rt][ct][1], 0.f);                                   \
        float v2 = fmaxf(acc[rt][ct][2], 0.f);                                   \
        float v3 = fmaxf(acc[rt][ct][3], 0.f);                                   \
        unsigned int p0, p1;                                                     \
        asm("v_cvt_pk_bf16_f32 %0, %1, %2" : "=v"(p0) : "v"(v0), "v"(v1));       \
        asm("v_cvt_pk_bf16_f32 %0, %1, %2" : "=v"(p1) : "v"(v2), "v"(v3));       \
        uint2 pk; pk.x = p0; pk.y = p1;                                          \
        *reinterpret_cast<uint2*>((DST) + ((sbase + (unsigned int)(n0 * 2)) ^ swz)) = pk; \
      }                                                                          \
    }                                                                            \
  }

__global__ __launch_bounds__(256, 2)
void mlp_kernel(const float* __restrict__ x, const float* __restrict__ h,
                const float* __restrict__ b0, const float* __restrict__ b1,
                const float* __restrict__ b2, const float* __restrict__ b3,
                const unsigned short* __restrict__ wp,
                const float* __restrict__ ccw,
                float* __restrict__ out) {
  __shared__ __align__(16) unsigned char ldsA[64 * 512];     // 32 KiB
  __shared__ __align__(16) unsigned char ldsB[64 * 512];     // 32 KiB
  __shared__ float ldsF[64];
  unsigned char* ldsIn = ldsB;         // layer-0 input overlays ldsB[0:4K]

  int tid  = threadIdx.x;
  int wv   = tid >> 6;
  int lane = tid & 63;
  int cgrp = wv;                 // 0..3 : 64-neuron group; wave owns all 64 rows
  int colb  = lane & 15;
  int khalf = lane >> 4;
  int blkbd = blockIdx.x * BDPB;

  const unsigned short* wb1p = wp + W0P_ELEMS;
  const unsigned short* wb2p = wp + W0P_ELEMS + W1P_ELEMS;
  const unsigned short* w3p  = wp + W0P_ELEMS + 2 * W1P_ELEMS;

  bf8 wa0, wa1, wa2, wa3, wb0, wb1, wb2, wb3;
  // layer-0 weights (single K-step) into slot A, issued before input staging
  LOADW4(wa0, wa1, wa2, wa3, wp, 0);

  // ---- stage layer-0 input: 63 real rows (3 bd x 21 s) + 1 zero pad row ----
  {
    int r = tid >> 2;                   // 0..63 (row within block)
    int q = tid & 3;                    // 8-col chunk
    unsigned int u = (unsigned int)r / NS;       // 0..2 (r=63 -> u=3)
    int s = r - (int)u * NS;
    int bd = blkbd + (int)u;
    us8 au = us8{0,0,0,0,0,0,0,0};
    if (r < 63 && bd < NBD) {
      float xv = x[bd];
      float node = xv * (cosf((float)s * 0.15707963267948966f) + 1.0f) * 0.5f;
      const float* hrow = h + bd * NCOND;
#pragma unroll
      for (int i = 0; i < 8; ++i) {
        int c = q * 8 + i;
        float v;
        if (c == 0)       v = node;
        else if (c <= 30) v = hrow[c - 1];
        else              v = 0.0f;
        au[i] = f2bf(v);
      }
    }
    unsigned int off = (unsigned int)(r * 64 + q * 16) ^ (unsigned int)((r & 3) << 4);
    *reinterpret_cast<us8*>(ldsIn + off) = au;
  }
  __syncthreads();

  fx4 acc[4][4];

  // ======== layer 0: K=32, read ldsIn(B), store ldsA — no mid barrier ========
  {
    ACC_BIAS(b0);
#pragma unroll
    for (int rt = 0; rt < 4; ++rt) {
      int m = rt * 16 + colb;
      unsigned int off = (unsigned int)(m * 64 + khalf * 16) ^ (unsigned int)((m & 3) << 4);
      bf8 a = *reinterpret_cast<const bf8*>(ldsIn + off);
      acc[rt][0] = __builtin_amdgcn_mfma_f32_16x16x32_bf16(wa0, a, acc[rt][0], 0, 0, 0);
      acc[rt][1] = __builtin_amdgcn_mfma_f32_16x16x32_bf16(wa1, a, acc[rt][1], 0, 0, 0);
      acc[rt][2] = __builtin_amdgcn_mfma_f32_16x16x32_bf16(wa2, a, acc[rt][2], 0, 0, 0);
      acc[rt][3] = __builtin_amdgcn_mfma_f32_16x16x32_bf16(wa3, a, acc[rt][3], 0, 0, 0);
    }
    // prefetch layer-1 kt0/kt1; loads straddle the store + barrier
    LOADW4(wa0, wa1, wa2, wa3, wb1p, 0);
    LOADW4(wb0, wb1, wb2, wb3, wb1p, 1);
    ACT_STORE(ldsA);                    // different buffer: no barrier needed
  }
  __syncthreads();

  // ======== layer 1: read ldsA, store ldsB (one barrier after stores) ========
  ACC_BIAS(b1);
  DENSE_PIPE(ldsA, wb1p, wb2p);          // tail prefetches layer-2 kt0/kt1
  ACT_STORE(ldsB);
  __syncthreads();

  // ======== layer 2: read ldsB, store ldsA ========
  ACC_BIAS(b2);
  DENSE_LAST(ldsB, wb2p);
  ACT_STORE(ldsA);
  __syncthreads();

  // ======== layer 3: 256 -> 1 via MFMA, wave wv handles rows wv*16..wv*16+15 ==
  {
    fx4 a3 = fx4{0.f, 0.f, 0.f, 0.f};
    int m = wv * 16 + colb;
    unsigned int abase = (unsigned int)(m * 512 + khalf * 16);
    unsigned int aswz  = (unsigned int)((m & 15) << 4);
#pragma unroll
    for (int kt = 0; kt < 8; ++kt) {
      bf8 w3f = *reinterpret_cast<const bf8*>(w3p + (kt * 64 + lane) * 8);
      bf8 a = *reinterpret_cast<const bf8*>(ldsA + ((abase + (unsigned)(kt * 64)) ^ aswz));
      a3 = __builtin_amdgcn_mfma_f32_16x16x32_bf16(w3f, a, a3, 0, 0, 0);
    }
    if (lane < 16) {
      float y = a3[0] + b3[0];
      float f = (y > 0.f) ? (y + 1.f) : expf(y);   // elu(y)+1
      ldsF[wv * 16 + lane] = f;
    }
  }
  __syncthreads();

  // ======== fused Clenshaw-Curtis reduction: 3 threads, one bd each ========
  if (tid < BDPB) {
    int bd = blkbd + tid;
    if (bd < NBD) {
      float acc2 = 0.f;
#pragma unroll
      for (int s2 = 0; s2 < NS; ++s2) acc2 += ldsF[tid * NS + s2] * ccw[s2];
      out[bd] = acc2 * x[bd] * 0.5f + h[bd * NCOND];  // z = z_est + h[:,:,0]
      out[NBD + bd] = ldsF[tid * NS];                 // jac = f at s=0
    }
  }
}

// ---------------- launcher ----------------
extern "C" void kernel_launch(void* const* d_in, const int* in_sizes, int n_in,
                              void* d_out, int out_size, void* d_ws, size_t ws_size,
                              hipStream_t stream) {
  (void)in_sizes; (void)n_in; (void)out_size; (void)ws_size;
  const float* x  = (const float*)d_in[0];
  const float* h  = (const float*)d_in[1];
  const float* W0 = (const float*)d_in[2];
  const float* b0 = (const float*)d_in[3];
  const float* W1 = (const float*)d_in[4];
  const float* b1 = (const float*)d_in[5];
  const float* W2 = (const float*)d_in[6];
  const float* b2 = (const float*)d_in[7];
  const float* W3 = (const float*)d_in[8];
  const float* b3 = (const float*)d_in[9];

  unsigned short* wp = (unsigned short*)d_ws;
  float* ccwbuf = (float*)((char*)d_ws + WP_TOTAL * sizeof(unsigned short));
  float* out  = (float*)d_out;

  prep_pack<<<(WP_TOTAL / 8 + 255) / 256, 256, 0, stream>>>(W0, W1, W2, W3, wp, ccwbuf);
  mlp_kernel<<<NBLK, 256, 0, stream>>>(x, h, b0, b1, b2, b3, wp, ccwbuf, out);
}